// Round 6
// baseline (253.418 us; speedup 1.0000x reference)
//
#include <hip/hip_runtime.h>
#include <hip/hip_bf16.h>
#include <math.h>

#define V 100000
#define H 256
#define B 512

typedef __bf16 bf16x8 __attribute__((ext_vector_type(8)));
typedef float  f32x4  __attribute__((ext_vector_type(4)));

__device__ __forceinline__ unsigned short f32_bf16_rne(float x) {
    unsigned u = __float_as_uint(x);
    u += 0x7FFFu + ((u >> 16) & 1u);            // round-to-nearest-even
    return (unsigned short)(u >> 16);
}
__device__ __forceinline__ float bf16u_f32(unsigned short h) {
    return __uint_as_float(((unsigned)h) << 16);
}
__device__ __forceinline__ float fast_tanh(float x) {
    // tanh(x) = 1 - 2/(exp2(x*2*log2e)+1); exp overflow/underflow saturate correctly
    float e = __builtin_exp2f(x * 2.8853900817779268f);
    return 1.f - 2.f * __builtin_amdgcn_rcpf(e + 1.f);
}

#define GLOAD_LDS16(g, l)                                                     \
    __builtin_amdgcn_global_load_lds(                                         \
        (const __attribute__((address_space(1))) void*)(g),                   \
        (__attribute__((address_space(3))) void*)(l), 16, 0, 0)

// ---------------------------------------------------------------------------
// Kernel 0 (prep): split w_out fp32 -> bf16 hi/lo planes in workspace.
// Pure streaming: 102 MB read + 102 MB write.
// ---------------------------------------------------------------------------
__global__ __launch_bounds__(256) void split_w_kernel(
    const float*    __restrict__ w,
    unsigned short* __restrict__ hi,
    unsigned short* __restrict__ lo)
{
    const int total4 = (V * H) / 4;   // 6,400,000 float4s
    for (int i = blockIdx.x * blockDim.x + threadIdx.x; i < total4;
         i += gridDim.x * blockDim.x) {
        const float4 x = reinterpret_cast<const float4*>(w)[i];
        const float f[4] = {x.x, x.y, x.z, x.w};
        ushort4 hv, lv;
        unsigned short* hp = &hv.x;
        unsigned short* lp = &lv.x;
        #pragma unroll
        for (int j = 0; j < 4; ++j) {
            hp[j] = f32_bf16_rne(f[j]);
            lp[j] = f32_bf16_rne(f[j] - bf16u_f32(hp[j]));
        }
        reinterpret_cast<ushort4*>(hi)[i] = hv;
        reinterpret_cast<ushort4*>(lo)[i] = lv;
    }
}

// ---------------------------------------------------------------------------
// Kernel 1: GRU cell (structure proven in rounds 3-5). One block per batch
// element; writes h_new into d_out + B*V, plus optional bf16 hi/lo planes.
// ---------------------------------------------------------------------------
__global__ __launch_bounds__(256) void gru_cell_kernel(
    const int*   __restrict__ input,
    const float* __restrict__ hidden,
    const float* __restrict__ w_ih,
    const float* __restrict__ w_hh,
    const float* __restrict__ b_ih,
    const float* __restrict__ b_hh,
    float*       __restrict__ h_out,
    unsigned short* __restrict__ h_hi_p,   // may be null (fallback path)
    unsigned short* __restrict__ h_lo_p)
{
    const int b = blockIdx.x;
    const int j = threadIdx.x;

    __shared__ float hs[H];
    hs[j] = hidden[b * H + j];
    __syncthreads();

    const int idx = input[b];
    float gi_r = w_ih[ j          * V + idx] + b_ih[j];
    float gi_z = w_ih[(j +     H) * V + idx] + b_ih[j + H];
    float gi_n = w_ih[(j + 2 * H) * V + idx] + b_ih[j + 2 * H];

    const float4* wr = reinterpret_cast<const float4*>(&w_hh[ j          * H]);
    const float4* wz = reinterpret_cast<const float4*>(&w_hh[(j +     H) * H]);
    const float4* wn = reinterpret_cast<const float4*>(&w_hh[(j + 2 * H) * H]);
    const float4* h4 = reinterpret_cast<const float4*>(hs);

    float ar = 0.f, az = 0.f, an = 0.f;
    #pragma unroll 8
    for (int k = 0; k < H / 4; ++k) {
        const float4 hv = h4[k];
        const float4 a  = wr[k];
        const float4 c  = wz[k];
        const float4 d  = wn[k];
        ar += a.x * hv.x + a.y * hv.y + a.z * hv.z + a.w * hv.w;
        az += c.x * hv.x + c.y * hv.y + c.z * hv.z + c.w * hv.w;
        an += d.x * hv.x + d.y * hv.y + d.z * hv.z + d.w * hv.w;
    }

    const float h_r = ar + b_hh[j];
    const float h_z = az + b_hh[j + H];
    const float h_n = an + b_hh[j + 2 * H];

    const float r = 1.f / (1.f + expf(-(gi_r + h_r)));
    const float z = 1.f / (1.f + expf(-(gi_z + h_z)));
    const float n = tanhf(gi_n + r * h_n);
    const float hprev = hs[j];

    const float val = (1.f - z) * n + z * hprev;
    h_out[b * H + j] = val;
    if (h_hi_p != nullptr) {
        const unsigned short hh = f32_bf16_rne(val);
        h_hi_p[b * H + j] = hh;
        h_lo_p[b * H + j] = f32_bf16_rne(val - bf16u_f32(hh));
    }
}

// ---------------------------------------------------------------------------
// Kernel 2 (new): logit = tanh(h_new @ w_out.T + b_out), split-bf16 MFMA,
// all operands pre-split into bf16 planes. Staging via global_load_lds w=16:
// lane-linear LDS dest + XOR-inverse-swizzled per-lane global source (rule 21),
// so the compute-side swizzled ds_read_b128 path is unchanged from round 4.
// Tile 64b x 128v, BK=64, 4 waves (2x2), 48 KB LDS -> 3 blocks/CU.
// ---------------------------------------------------------------------------
#define BM  64
#define BN  128
#define BK  64
#define NVB 782   // ceil(V/BN)
#define NBB 8     // B/BM

__global__ __launch_bounds__(256) void out_gemm_lds(
    const unsigned short* __restrict__ whi_g,  // (V,H) bf16 hi plane
    const unsigned short* __restrict__ wlo_g,  // (V,H) bf16 lo plane
    const unsigned short* __restrict__ hhi_g,  // (B,H) bf16 hi plane
    const unsigned short* __restrict__ hlo_g,  // (B,H) bf16 lo plane
    const float*          __restrict__ b_out,  // (V)
    float*                __restrict__ logit)  // (B,V)
{
    __shared__ unsigned short w_hi_s[BN * BK];   // 16 KB
    __shared__ unsigned short w_lo_s[BN * BK];   // 16 KB
    __shared__ unsigned short h_hi_s[BM * BK];   //  8 KB
    __shared__ unsigned short h_lo_s[BM * BK];   //  8 KB

    const int tid  = threadIdx.x;
    const int lane = tid & 63;
    const int wid  = tid >> 6;
    const int wm   = wid >> 1;      // batch half (0..1)
    const int wn   = wid & 1;       // vocab half (0..1)

    // XCD-chunked bijective swizzle, batch-fastest (proven: FETCH 820->53 MB).
    const int bid = blockIdx.x;                    // 0..6255
    const int wg  = (bid & 7) * NVB + (bid >> 3);
    const int bx  = wg & 7;                        // batch block
    const int by  = wg >> 3;                       // vocab block
    const int b0  = bx * BM;
    const int v0  = by * BN;

    // ---- staging: 12 global_load_lds per K-chunk, zero VALU conversions ----
    auto stage = [&](int k0) {
        #pragma unroll
        for (int i = 0; i < 4; ++i) {              // w planes: 4 issues each
            const int p    = i * 4096 + (wid << 10) + (lane << 4);
            const int row  = p >> 7;               // local vocab row 0..127
            const int lb   = p & 127;
            const int swz  = lb ^ ((row & 7) << 4);
            int vg = v0 + row; if (vg > V - 1) vg = V - 1;
            const size_t gb = (size_t)vg * (H * 2) + (size_t)(k0 * 2) + swz;
            const int dst  = i * 4096 + (wid << 10);
            GLOAD_LDS16((const char*)whi_g + gb, (char*)w_hi_s + dst);
            GLOAD_LDS16((const char*)wlo_g + gb, (char*)w_lo_s + dst);
        }
        #pragma unroll
        for (int i = 0; i < 2; ++i) {              // h planes: 2 issues each
            const int p    = i * 4096 + (wid << 10) + (lane << 4);
            const int row  = p >> 7;               // local batch row 0..63
            const int lb   = p & 127;
            const int swz  = lb ^ ((row & 7) << 4);
            const size_t gb = (size_t)(b0 + row) * (H * 2) + (size_t)(k0 * 2) + swz;
            const int dst  = i * 4096 + (wid << 10);
            GLOAD_LDS16((const char*)hhi_g + gb, (char*)h_hi_s + dst);
            GLOAD_LDS16((const char*)hlo_g + gb, (char*)h_lo_s + dst);
        }
    };

    f32x4 acc[2][4];
    #pragma unroll
    for (int i = 0; i < 2; ++i)
        #pragma unroll
        for (int n = 0; n < 4; ++n)
            acc[i][n] = f32x4{0.f, 0.f, 0.f, 0.f};

    auto compute = [&]() {
        #pragma unroll
        for (int ks = 0; ks < 2; ++ks) {
            const int kb = ks * 64 + (lane >> 4) * 16;   // k byte offset
            bf16x8 ah[2], al[2];
            #pragma unroll
            for (int i = 0; i < 2; ++i) {
                const int row = wm * 32 + i * 16 + (lane & 15);
                const int off = row * (BK * 2) + (kb ^ ((row & 7) << 4));
                ah[i] = *reinterpret_cast<const bf16x8*>(
                            reinterpret_cast<const char*>(h_hi_s) + off);
                al[i] = *reinterpret_cast<const bf16x8*>(
                            reinterpret_cast<const char*>(h_lo_s) + off);
            }
            #pragma unroll
            for (int n = 0; n < 4; ++n) {
                const int row = wn * 64 + n * 16 + (lane & 15);
                const int off = row * (BK * 2) + (kb ^ ((row & 7) << 4));
                const bf16x8 bh = *reinterpret_cast<const bf16x8*>(
                            reinterpret_cast<const char*>(w_hi_s) + off);
                const bf16x8 bl = *reinterpret_cast<const bf16x8*>(
                            reinterpret_cast<const char*>(w_lo_s) + off);
                #pragma unroll
                for (int i = 0; i < 2; ++i) {
                    acc[i][n] = __builtin_amdgcn_mfma_f32_16x16x32_bf16(ah[i], bh, acc[i][n], 0, 0, 0);
                    acc[i][n] = __builtin_amdgcn_mfma_f32_16x16x32_bf16(ah[i], bl, acc[i][n], 0, 0, 0);
                    acc[i][n] = __builtin_amdgcn_mfma_f32_16x16x32_bf16(al[i], bh, acc[i][n], 0, 0, 0);
                }
            }
        }
    };

    // m97-style 2-barrier loop; cross-block overlap from 3 blocks/CU.
    #pragma unroll
    for (int t = 0; t < 4; ++t) {
        stage(t * BK);
        __syncthreads();            // vmcnt(0) drain + barrier: LDS ready
        compute();
        __syncthreads();            // reads done before next stage overwrites
    }

    // Epilogue: bias + tanh + masked store. C/D: col=lane&15, row=(lane>>4)*4+r.
    float bias[4];
    int   cols[4];
    #pragma unroll
    for (int n = 0; n < 4; ++n) {
        const int c = v0 + wn * 64 + n * 16 + (lane & 15);
        cols[n] = c;
        bias[n] = (c < V) ? b_out[c] : 0.f;
    }
    const int rbase = b0 + wm * 32 + (lane >> 4) * 4;
    #pragma unroll
    for (int i = 0; i < 2; ++i) {
        #pragma unroll
        for (int r = 0; r < 4; ++r) {
            const int row = rbase + i * 16 + r;
            float* dst = logit + (size_t)row * V;
            #pragma unroll
            for (int n = 0; n < 4; ++n) {
                if (cols[n] < V)
                    dst[cols[n]] = fast_tanh(acc[i][n][r] + bias[n]);
            }
        }
    }
}

// ---------------------------------------------------------------------------
// Fallback kernel (round-4, proven): reg-staged split-bf16 GEMM, used only if
// ws_size can't hold the planes.
// ---------------------------------------------------------------------------
__global__ __launch_bounds__(256) void out_gemm_mfma_reg(
    const float* __restrict__ hnew,
    const float* __restrict__ w_out,
    const float* __restrict__ b_out,
    float*       __restrict__ logit)
{
    __shared__ unsigned short w_hi[BN * BK];
    __shared__ unsigned short w_lo[BN * BK];
    __shared__ unsigned short h_hi[BM * BK];
    __shared__ unsigned short h_lo[BM * BK];

    const int tid  = threadIdx.x;
    const int lane = tid & 63;
    const int wid  = tid >> 6;
    const int wm   = wid >> 1;
    const int wn   = wid & 1;

    const int bid = blockIdx.x;
    const int wg  = (bid & 7) * NVB + (bid >> 3);
    const int bx  = wg & 7;
    const int by  = wg >> 3;
    const int b0  = bx * BM;
    const int v0  = by * BN;

    float4 wreg[8];
    float4 hreg[4];

    auto load_chunk = [&](int k0) {
        #pragma unroll
        for (int i = 0; i < 8; ++i) {
            const int idx4 = i * 256 + tid;
            const int row  = idx4 >> 4;
            const int k4   = (idx4 & 15) << 2;
            int vg = v0 + row; if (vg > V - 1) vg = V - 1;
            wreg[i] = *reinterpret_cast<const float4*>(&w_out[(size_t)vg * H + k0 + k4]);
        }
        #pragma unroll
        for (int i = 0; i < 4; ++i) {
            const int idx4 = i * 256 + tid;
            const int row  = idx4 >> 4;
            const int k4   = (idx4 & 15) << 2;
            hreg[i] = *reinterpret_cast<const float4*>(&hnew[(b0 + row) * H + k0 + k4]);
        }
    };

    auto store_chunk = [&]() {
        #pragma unroll
        for (int i = 0; i < 8; ++i) {
            const int idx4 = i * 256 + tid;
            const int row  = idx4 >> 4;
            const int k4   = (idx4 & 15) << 2;
            const int off  = row * (BK * 2) + ((k4 * 2) ^ ((row & 7) << 4));
            const float f[4] = {wreg[i].x, wreg[i].y, wreg[i].z, wreg[i].w};
            unsigned short hv[4], lv[4];
            #pragma unroll
            for (int j = 0; j < 4; ++j) {
                hv[j] = f32_bf16_rne(f[j]);
                lv[j] = f32_bf16_rne(f[j] - bf16u_f32(hv[j]));
            }
            *reinterpret_cast<ushort4*>(reinterpret_cast<char*>(w_hi) + off) =
                make_ushort4(hv[0], hv[1], hv[2], hv[3]);
            *reinterpret_cast<ushort4*>(reinterpret_cast<char*>(w_lo) + off) =
                make_ushort4(lv[0], lv[1], lv[2], lv[3]);
        }
        #pragma unroll
        for (int i = 0; i < 4; ++i) {
            const int idx4 = i * 256 + tid;
            const int row  = idx4 >> 4;
            const int k4   = (idx4 & 15) << 2;
            const int off  = row * (BK * 2) + ((k4 * 2) ^ ((row & 7) << 4));
            const float f[4] = {hreg[i].x, hreg[i].y, hreg[i].z, hreg[i].w};
            unsigned short hv[4], lv[4];
            #pragma unroll
            for (int j = 0; j < 4; ++j) {
                hv[j] = f32_bf16_rne(f[j]);
                lv[j] = f32_bf16_rne(f[j] - bf16u_f32(hv[j]));
            }
            *reinterpret_cast<ushort4*>(reinterpret_cast<char*>(h_hi) + off) =
                make_ushort4(hv[0], hv[1], hv[2], hv[3]);
            *reinterpret_cast<ushort4*>(reinterpret_cast<char*>(h_lo) + off) =
                make_ushort4(lv[0], lv[1], lv[2], lv[3]);
        }
    };

    f32x4 acc[2][4];
    #pragma unroll
    for (int i = 0; i < 2; ++i)
        #pragma unroll
        for (int n = 0; n < 4; ++n)
            acc[i][n] = f32x4{0.f, 0.f, 0.f, 0.f};

    auto compute = [&]() {
        #pragma unroll
        for (int ks = 0; ks < 2; ++ks) {
            const int kb = ks * 64 + (lane >> 4) * 16;
            bf16x8 ah[2], al[2];
            #pragma unroll
            for (int i = 0; i < 2; ++i) {
                const int row = wm * 32 + i * 16 + (lane & 15);
                const int off = row * (BK * 2) + (kb ^ ((row & 7) << 4));
                ah[i] = *reinterpret_cast<const bf16x8*>(
                            reinterpret_cast<const char*>(h_hi) + off);
                al[i] = *reinterpret_cast<const bf16x8*>(
                            reinterpret_cast<const char*>(h_lo) + off);
            }
            #pragma unroll
            for (int n = 0; n < 4; ++n) {
                const int row = wn * 64 + n * 16 + (lane & 15);
                const int off = row * (BK * 2) + (kb ^ ((row & 7) << 4));
                const bf16x8 bh = *reinterpret_cast<const bf16x8*>(
                            reinterpret_cast<const char*>(w_hi) + off);
                const bf16x8 bl = *reinterpret_cast<const bf16x8*>(
                            reinterpret_cast<const char*>(w_lo) + off);
                #pragma unroll
                for (int i = 0; i < 2; ++i) {
                    acc[i][n] = __builtin_amdgcn_mfma_f32_16x16x32_bf16(ah[i], bh, acc[i][n], 0, 0, 0);
                    acc[i][n] = __builtin_amdgcn_mfma_f32_16x16x32_bf16(ah[i], bl, acc[i][n], 0, 0, 0);
                    acc[i][n] = __builtin_amdgcn_mfma_f32_16x16x32_bf16(al[i], bh, acc[i][n], 0, 0, 0);
                }
            }
        }
    };

    load_chunk(0);
    store_chunk();
    __syncthreads();
    for (int t = 0; t < 4; ++t) {
        if (t < 3) load_chunk((t + 1) * BK);
        compute();
        __syncthreads();
        if (t < 3) { store_chunk(); __syncthreads(); }
    }

    float bias[4];
    int   cols[4];
    #pragma unroll
    for (int n = 0; n < 4; ++n) {
        const int c = v0 + wn * 64 + n * 16 + (lane & 15);
        cols[n] = c;
        bias[n] = (c < V) ? b_out[c] : 0.f;
    }
    const int rbase = b0 + wm * 32 + (lane >> 4) * 4;
    #pragma unroll
    for (int i = 0; i < 2; ++i) {
        #pragma unroll
        for (int r = 0; r < 4; ++r) {
            const int row = rbase + i * 16 + r;
            float* dst = logit + (size_t)row * V;
            #pragma unroll
            for (int n = 0; n < 4; ++n) {
                if (cols[n] < V)
                    dst[cols[n]] = tanhf(acc[i][n][r] + bias[n]);
            }
        }
    }
}

// ---------------------------------------------------------------------------
extern "C" void kernel_launch(void* const* d_in, const int* in_sizes, int n_in,
                              void* d_out, int out_size, void* d_ws, size_t ws_size,
                              hipStream_t stream) {
    const int*   input  = (const int*)  d_in[0];
    // d_in[1] = target (unused by forward)
    const float* hidden = (const float*)d_in[2];
    const float* w_ih   = (const float*)d_in[3];
    const float* w_hh   = (const float*)d_in[4];
    const float* b_ih   = (const float*)d_in[5];
    const float* b_hh   = (const float*)d_in[6];
    const float* w_out  = (const float*)d_in[7];
    const float* b_out  = (const float*)d_in[8];

    float* out   = (float*)d_out;
    float* logit = out;                      // first B*V floats
    float* h_new = out + (size_t)B * V;      // then L*B*H floats (L=1)

    const size_t nw = (size_t)V * H;         // 25,600,000
    const size_t nh = (size_t)B * H;         // 131,072
    const size_t needed = (2 * nw + 2 * nh) * sizeof(unsigned short); // ~103 MB

    if (ws_size >= needed) {
        unsigned short* whi = (unsigned short*)d_ws;
        unsigned short* wlo = whi + nw;
        unsigned short* hhi = wlo + nw;
        unsigned short* hlo = hhi + nh;

        split_w_kernel<<<2048, 256, 0, stream>>>(w_out, whi, wlo);
        gru_cell_kernel<<<B, 256, 0, stream>>>(input, hidden, w_ih, w_hh,
                                               b_ih, b_hh, h_new, hhi, hlo);
        out_gemm_lds<<<NVB * NBB, 256, 0, stream>>>(whi, wlo, hhi, hlo,
                                                    b_out, logit);
    } else {
        gru_cell_kernel<<<B, 256, 0, stream>>>(input, hidden, w_ih, w_hh,
                                               b_ih, b_hh, h_new,
                                               nullptr, nullptr);
        out_gemm_mfma_reg<<<NVB * NBB, 256, 0, stream>>>(h_new, w_out,
                                                         b_out, logit);
    }
}